// Round 4
// baseline (104.245 us; speedup 1.0000x reference)
//
#include <hip/hip_runtime.h>
#include <stdint.h>

#define NATOMS 4096
#define NCELLS 8000
#define KTOP 5
#define MNBR 8
#define NBRC 26
#define HBINS 217          // histogram window [Dmax-216, Dmax]
#define LSTMAX 512
#define FXSCALE 1048576.0f // 2^20 fixed-point for deterministic energy sum

__device__ __forceinline__ unsigned long long umax64(unsigned long long a, unsigned long long b) {
    return a > b ? a : b;
}
__device__ __forceinline__ unsigned long long umin64(unsigned long long a, unsigned long long b) {
    return a < b ? a : b;
}

// cells[m] = (g[b], g[c], g[a]) with m = a*400 + b*20 + c, g[t] = t-10
__device__ __forceinline__ void cell_coords_i(int m, int& x, int& y, int& z) {
    int a = m / 400;
    int r = m - a * 400;
    int b = r / 20;
    int c = r - b * 20;
    x = b - 10; y = c - 10; z = a - 10;
}

// ---------------------------------------------------------------------------
// Kernel C: analytic argmin cell (4x4x4 neighborhood of floor(atom); exact
// d^2 gap >= 1.0 dwarfs f32 expansion error). Same f32 formula + min-key as
// the full scan -> bitwise identical. Also zeroes neededFlag / acc / done
// for this call (consumed only by LATER kernels -> no race).
// ---------------------------------------------------------------------------
__global__ __launch_bounds__(256) void kcellsforatoms(const float* __restrict__ coords,
                                                      int* __restrict__ cellsForAtoms,
                                                      int* __restrict__ neededFlag,
                                                      unsigned long long* __restrict__ acc,
                                                      int* __restrict__ done) {
    {
        int z = blockIdx.x * 8 + threadIdx.x;
        if (threadIdx.x < 8 && z < NCELLS) neededFlag[z] = 0;
        if (blockIdx.x == 0 && threadIdx.x == 8) *acc = 0ull;
        if (blockIdx.x == 0 && threadIdx.x == 9) *done = 0;
    }
    const int wid = threadIdx.x >> 6;
    const int lane = threadIdx.x & 63;
    const int atom = blockIdx.x * 4 + wid;

    float ax = coords[atom * 3], ay = coords[atom * 3 + 1], az = coords[atom * 3 + 2];
    float sa = __fadd_rn(__fadd_rn(__fmul_rn(ax, ax), __fmul_rn(ay, ay)), __fmul_rn(az, az));

    int fx = (int)floorf(ax), fy = (int)floorf(ay), fz = (int)floorf(az);
    int vx = min(9, max(-10, fx - 1 + (lane & 3)));
    int vy = min(9, max(-10, fy - 1 + ((lane >> 2) & 3)));
    int vz = min(9, max(-10, fz - 1 + (lane >> 4)));
    int m = (vz + 10) * 400 + (vx + 10) * 20 + (vy + 10);

    float cx = (float)vx, cy = (float)vy, cz = (float)vz;
    float scell = (float)(vx * vx + vy * vy + vz * vz);
    float dot = __fadd_rn(__fadd_rn(__fmul_rn(ax, cx), __fmul_rn(ay, cy)), __fmul_rn(az, cz));
    float val = __fsub_rn(__fadd_rn(sa, scell), __fmul_rn(2.0f, dot));
    unsigned long long key = ((unsigned long long)__float_as_uint(val) << 32) | (unsigned int)m;

    for (int off = 32; off > 0; off >>= 1)
        key = umin64(key, (unsigned long long)__shfl_xor((long long)key, off));
    if (lane == 0) cellsForAtoms[atom] = (int)(key & 0xFFFFFFFFull);
}

// ---------------------------------------------------------------------------
// Kernel A: top-26 LARGEST cell-cell sq-dists. One block per ATOM (blocks
// sharing a cell write identical rows - benign). Windowed histogram -> cutoff
// V -> collect d>=V into LDS list -> single-wave rank-select by packed key
// (d desc, j asc) == jax.lax.top_k tie order. No extraction rounds.
// ---------------------------------------------------------------------------
__global__ __launch_bounds__(256) void knbr2(const int* __restrict__ cellsForAtoms,
                                             int* __restrict__ nbrTable,
                                             int* __restrict__ neededFlag) {
    const int ci = cellsForAtoms[blockIdx.x];
    const int t = threadIdx.x;
    const int lane = t & 63;

    int xi, yi, zi;
    cell_coords_i(ci, xi, yi, zi);
    const int Mx = max((xi + 10) * (xi + 10), (9 - xi) * (9 - xi));
    const int My = max((yi + 10) * (yi + 10), (9 - yi) * (9 - yi));
    const int Mz = max((zi + 10) * (zi + 10), (9 - zi) * (9 - zi));
    const int lo = Mx + My + Mz - (HBINS - 1);   // 26th-largest >= lo (proof: 27
                                                 // cells from top-3 per-dim vals)
    __shared__ uint32_t h[HBINS];
    __shared__ int lst[LSTMAX];
    __shared__ int sV, cnt;

    if (t < HBINS) h[t] = 0;
    if (t == 0) cnt = 0;
    __syncthreads();

    // generation pass: thread covers (b,c) columns t and t+256
#pragma unroll
    for (int col = 0; col < 2; ++col) {
        int p = t + 256 * col;
        if (p < 400) {
            int bb = p / 20, cc = p - bb * 20;
            int dxv = xi - (bb - 10), dyv = yi - (cc - 10);
            int Dbc = dxv * dxv + dyv * dyv;
#pragma unroll
            for (int a = 0; a < 20; ++a) {
                int dzv = zi - (a - 10);
                int d = Dbc + dzv * dzv;
                if (d >= lo) atomicAdd(&h[d - lo], 1u);
            }
        }
    }
    __syncthreads();

    // single-wave descending scan: V = largest value with suffix-count >= 26
    if (t < 64) {
        int c4[4];
        int cnt4 = 0;
#pragma unroll
        for (int k = 0; k < 4; ++k) {
            int b = (HBINS - 1) - (t * 4 + k);
            c4[k] = (b >= 0) ? (int)h[b] : 0;
            cnt4 += c4[k];
        }
        int incl = cnt4;
        for (int off = 1; off < 64; off <<= 1) {
            int v = __shfl_up(incl, off);
            if (lane >= off) incl += v;
        }
        int P = incl - cnt4;                 // count strictly above my chunk
        if (P < NBRC && incl >= NBRC) {
            int run = P;
#pragma unroll
            for (int k = 0; k < 4; ++k) {
                run += c4[k];
                if (run >= NBRC) { sV = lo + (HBINS - 1) - (t * 4 + k); break; }
            }
        }
    }
    __syncthreads();
    const int V = sV;

    // collect pass: all items with d >= V (count = n1 + ties, << LSTMAX)
#pragma unroll
    for (int col = 0; col < 2; ++col) {
        int p = t + 256 * col;
        if (p < 400) {
            int bb = p / 20, cc = p - bb * 20;
            int dxv = xi - (bb - 10), dyv = yi - (cc - 10);
            int Dbc = dxv * dxv + dyv * dyv;
#pragma unroll
            for (int a = 0; a < 20; ++a) {
                int dzv = zi - (a - 10);
                int d = Dbc + dzv * dzv;
                if (d >= V) {
                    int j = a * 400 + p;
                    int q = atomicAdd(&cnt, 1);
                    if (q < LSTMAX) lst[q] = (d << 13) | (8191 - j);
                }
            }
        }
    }
    __syncthreads();

    // single-wave rank selection: ranks 0..25 are the top-26 in key order
    int n = min(cnt, LSTMAX);
    if (t < 64) {
        for (int base = 0; base < n; base += 64) {
            int idx = base + t;
            int key = (idx < n) ? lst[idx] : -1;
            int rank = 0;
            for (int m = 0; m < n; ++m) rank += (lst[m] > key) ? 1 : 0;
            if (idx < n && rank < NBRC) {
                int j = 8191 - (key & 8191);
                nbrTable[ci * NBRC + rank] = j;
                neededFlag[j] = 1;
            }
        }
    }
}

// ---------------------------------------------------------------------------
// Kernel B: atoms_in_cells = top-5 LARGEST atom distances for NEEDED cells.
// ---------------------------------------------------------------------------
__global__ __launch_bounds__(256) void katoms2(const float* __restrict__ coords,
                                               const int* __restrict__ neededFlag,
                                               int* __restrict__ atomsInCells) {
    const int i = blockIdx.x;
    if (!neededFlag[i]) return;
    __shared__ unsigned long long redB[4];
    const int t = threadIdx.x;
    const int lane = t & 63, wv = t >> 6;

    int xi_, yi_, zi_;
    cell_coords_i(i, xi_, yi_, zi_);
    const float cx = (float)xi_, cy = (float)yi_, cz = (float)zi_;
    const float scell = (float)(xi_ * xi_ + yi_ * yi_ + zi_ * zi_);

    unsigned long long keys[16];
#pragma unroll
    for (int s = 0; s < 16; ++s) {
        int j = t + 256 * s;
        float ax = coords[j * 3], ay = coords[j * 3 + 1], az = coords[j * 3 + 2];
        float sa = __fadd_rn(__fadd_rn(__fmul_rn(ax, ax), __fmul_rn(ay, ay)), __fmul_rn(az, az));
        float dot = __fadd_rn(__fadd_rn(__fmul_rn(cx, ax), __fmul_rn(cy, ay)), __fmul_rn(cz, az));
        float val = __fsub_rn(__fadd_rn(scell, sa), __fmul_rn(2.0f, dot));
        keys[s] = ((unsigned long long)__float_as_uint(val) << 32) | (unsigned int)(4095 - j);
    }

    for (int r = 0; r < KTOP; ++r) {
        unsigned long long best = 0ull;
#pragma unroll
        for (int s = 0; s < 16; ++s) best = umax64(best, keys[s]);
        for (int off = 32; off > 0; off >>= 1)
            best = umax64(best, (unsigned long long)__shfl_xor((long long)best, off));
        if (lane == 0) redB[wv] = best;
        __syncthreads();
        unsigned long long wbest = umax64(umax64(redB[0], redB[1]), umax64(redB[2], redB[3]));
        if (t == 0) atomsInCells[i * KTOP + r] = 4095 - (int)(wbest & 0xFFFFFFFFull);
#pragma unroll
        for (int s = 0; s < 16; ++s) if (keys[s] == wbest) keys[s] = 0ull;
        __syncthreads();
    }
}

// ---------------------------------------------------------------------------
// Kernel D: per-atom top-8 + energy, fused final reduction (fixed-point
// integer atomics -> deterministic; last block divides and writes out).
// ---------------------------------------------------------------------------
__global__ __launch_bounds__(256) void kenergy(const float* __restrict__ coords,
                                               const float* __restrict__ vdw,
                                               const float* __restrict__ weights,
                                               const float* __restrict__ nrot,
                                               const int* __restrict__ nbrTable,
                                               const int* __restrict__ atomsInCells,
                                               const int* __restrict__ cellsForAtoms,
                                               unsigned long long* __restrict__ acc,
                                               int* __restrict__ done,
                                               float* __restrict__ out) {
    const int wid = threadIdx.x >> 6;
    const int lane = threadIdx.x & 63;
    const int i = blockIdx.x * 4 + wid;

    const float xi = coords[i * 3], yi = coords[i * 3 + 1], zi = coords[i * 3 + 2];
    const int ci = cellsForAtoms[i];

    int cand[3];
    unsigned long long keys[3];
#pragma unroll
    for (int s = 0; s < 3; ++s) {
        int p = lane + 64 * s;
        cand[s] = -1;
        keys[s] = 0ull;
        if (p < NBRC * KTOP) {
            int cellSlot = p / KTOP;
            int atomSlot = p - cellSlot * KTOP;
            int nc = nbrTable[ci * NBRC + cellSlot];
            int j = atomsInCells[nc * KTOP + atomSlot];
            cand[s] = j;
            float dx = __fsub_rn(xi, coords[j * 3]);
            float dy = __fsub_rn(yi, coords[j * 3 + 1]);
            float dz = __fsub_rn(zi, coords[j * 3 + 2]);
            float dist = __fadd_rn(__fadd_rn(__fmul_rn(dx, dx), __fmul_rn(dy, dy)), __fmul_rn(dz, dz));
            keys[s] = ((unsigned long long)__float_as_uint(dist) << 8) | (unsigned int)(255 - p);
        }
    }

    const float w0 = weights[0], w1 = weights[1], w2 = weights[2];
    const float w3 = weights[3], w4 = weights[4];
    const float vi = vdw[i];

    float esum = 0.0f;
    for (int r = 0; r < MNBR; ++r) {
        unsigned long long best = umax64(umax64(keys[0], keys[1]), keys[2]);
        for (int off = 32; off > 0; off >>= 1)
            best = umax64(best, (unsigned long long)__shfl_xor((long long)best, off));

        int p = 255 - (int)(best & 0xFFull);
        int slot = p >> 6;
        int owner = p & 63;
        int jsel = (slot == 0) ? cand[0] : (slot == 1) ? cand[1] : cand[2];
        int j = __shfl(jsel, owner);
        float dist = __uint_as_float((unsigned int)(best >> 8));

#pragma unroll
        for (int s = 0; s < 3; ++s) if (keys[s] == best) keys[s] = 0ull;

        float rr = __fsqrt_rn(__fadd_rn(dist, 1e-12f));
        float d = __fsub_rn(__fsub_rn(rr, vi), vdw[j]);
        float t1 = __fdiv_rn(d, 0.5f);
        float g1 = expf(-__fmul_rn(t1, t1));
        float t2 = __fdiv_rn(__fsub_rn(d, 3.0f), 2.0f);
        float g2 = expf(-__fmul_rn(t2, t2));
        float rep = (d < 0.0f) ? __fmul_rn(d, d) : 0.0f;
        float hyd = (d < 0.5f) ? 1.0f : ((d < 1.5f) ? __fsub_rn(1.5f, d) : 0.0f);
        float hb = (d < -0.7f) ? 1.0f : ((d < 0.0f) ? __fdiv_rn(-d, 0.7f) : 0.0f);
        float hval = __fadd_rn(__fadd_rn(__fadd_rn(__fadd_rn(
                         __fmul_rn(w0, g1), __fmul_rn(w1, g2)),
                         __fmul_rn(w2, rep)), __fmul_rn(w3, hyd)), __fmul_rn(w4, hb));
        float f = (d < 8.0f) ? hval : 0.0f;
        esum = __fadd_rn(esum, f);
    }
    if (lane == 0) {
        long long q = llrintf(__fmul_rn(esum, FXSCALE));
        atomicAdd(acc, (unsigned long long)q);
    }
    __syncthreads();
    if (threadIdx.x == 0) {
        __threadfence();
        int old = atomicAdd(done, 1);
        if (old == (int)gridDim.x - 1) {
            __threadfence();
            unsigned long long v = atomicAdd(acc, 0ull);
            double c = (double)(long long)v * (1.0 / 1048576.0);
            out[0] = __fdiv_rn((float)c, __fadd_rn(1.0f, __fmul_rn(weights[5], nrot[0])));
        }
    }
}

extern "C" void kernel_launch(void* const* d_in, const int* in_sizes, int n_in,
                              void* d_out, int out_size, void* d_ws, size_t ws_size,
                              hipStream_t stream) {
    const float* coords  = (const float*)d_in[0];
    const float* vdw     = (const float*)d_in[1];
    const float* weights = (const float*)d_in[2];
    const float* nrot    = (const float*)d_in[3];
    float* out = (float*)d_out;

    unsigned long long* acc = (unsigned long long*)d_ws;   // 8B, aligned
    int* done          = (int*)(acc + 1);                  // 1
    int* nbrTable      = done + 1;                         // 208000
    int* atomsInCells  = nbrTable + NCELLS * NBRC;         // 40000
    int* cellsForAtoms = atomsInCells + NCELLS * KTOP;     // 4096
    int* neededFlag    = cellsForAtoms + NATOMS;           // 8000

    kcellsforatoms<<<NATOMS / 4, 256, 0, stream>>>(coords, cellsForAtoms, neededFlag, acc, done);
    knbr2<<<NATOMS, 256, 0, stream>>>(cellsForAtoms, nbrTable, neededFlag);
    katoms2<<<NCELLS, 256, 0, stream>>>(coords, neededFlag, atomsInCells);
    kenergy<<<NATOMS / 4, 256, 0, stream>>>(coords, vdw, weights, nrot, nbrTable,
                                            atomsInCells, cellsForAtoms, acc, done, out);
}

// Round 5
// 47.396 us; speedup vs baseline: 2.1994x; 2.1994x over previous
//
#include <hip/hip_runtime.h>
#include <stdint.h>

#define NATOMS 4096
#define NCELLS 8000
#define KTOP 5
#define MNBR 8
#define NBRC 26
#define HBINS 217          // histogram window [Dmax-216, Dmax]
#define LSTMAX 512

__device__ __forceinline__ unsigned long long umax64(unsigned long long a, unsigned long long b) {
    return a > b ? a : b;
}
__device__ __forceinline__ unsigned long long umin64(unsigned long long a, unsigned long long b) {
    return a < b ? a : b;
}

// cells[m] = (g[b], g[c], g[a]) with m = a*400 + b*20 + c, g[t] = t-10
__device__ __forceinline__ void cell_coords_i(int m, int& x, int& y, int& z) {
    int a = m / 400;
    int r = m - a * 400;
    int b = r / 20;
    int c = r - b * 20;
    x = b - 10; y = c - 10; z = a - 10;
}

// ---------------------------------------------------------------------------
// Kernel C: analytic argmin cell (4x4x4 neighborhood of floor(atom); exact
// d^2 gap >= 1.0 dwarfs f32 expansion error ~2e-4). Same f32 formula +
// (bits<<32)|m min-key as the 8000-cell scan -> bitwise identical result.
// Also zeroes neededFlag (consumed only by later kernels -> no race).
// ---------------------------------------------------------------------------
__global__ __launch_bounds__(256) void kcellsforatoms(const float* __restrict__ coords,
                                                      int* __restrict__ cellsForAtoms,
                                                      int* __restrict__ neededFlag) {
    {
        int z = blockIdx.x * 8 + threadIdx.x;
        if (threadIdx.x < 8 && z < NCELLS) neededFlag[z] = 0;
    }
    const int wid = threadIdx.x >> 6;
    const int lane = threadIdx.x & 63;
    const int atom = blockIdx.x * 4 + wid;

    float ax = coords[atom * 3], ay = coords[atom * 3 + 1], az = coords[atom * 3 + 2];
    float sa = __fadd_rn(__fadd_rn(__fmul_rn(ax, ax), __fmul_rn(ay, ay)), __fmul_rn(az, az));

    int fx = (int)floorf(ax), fy = (int)floorf(ay), fz = (int)floorf(az);
    int vx = min(9, max(-10, fx - 1 + (lane & 3)));
    int vy = min(9, max(-10, fy - 1 + ((lane >> 2) & 3)));
    int vz = min(9, max(-10, fz - 1 + (lane >> 4)));
    int m = (vz + 10) * 400 + (vx + 10) * 20 + (vy + 10);

    float cx = (float)vx, cy = (float)vy, cz = (float)vz;
    float scell = (float)(vx * vx + vy * vy + vz * vz);
    float dot = __fadd_rn(__fadd_rn(__fmul_rn(ax, cx), __fmul_rn(ay, cy)), __fmul_rn(az, cz));
    float val = __fsub_rn(__fadd_rn(sa, scell), __fmul_rn(2.0f, dot));
    unsigned long long key = ((unsigned long long)__float_as_uint(val) << 32) | (unsigned int)m;

    for (int off = 32; off > 0; off >>= 1)
        key = umin64(key, (unsigned long long)__shfl_xor((long long)key, off));
    if (lane == 0) cellsForAtoms[atom] = (int)(key & 0xFFFFFFFFull);
}

// ---------------------------------------------------------------------------
// Kernel A: top-26 LARGEST cell-cell sq-dists. One block per ATOM (blocks
// sharing a cell write identical rows - benign). Windowed histogram -> cutoff
// V -> collect d>=V into LDS list -> single-wave rank-select by packed key
// (d desc, j asc) == jax.lax.top_k tie order. No extraction rounds.
// ---------------------------------------------------------------------------
__global__ __launch_bounds__(256) void knbr2(const int* __restrict__ cellsForAtoms,
                                             int* __restrict__ nbrTable,
                                             int* __restrict__ neededFlag) {
    const int ci = cellsForAtoms[blockIdx.x];
    const int t = threadIdx.x;
    const int lane = t & 63;

    int xi, yi, zi;
    cell_coords_i(ci, xi, yi, zi);
    const int Mx = max((xi + 10) * (xi + 10), (9 - xi) * (9 - xi));
    const int My = max((yi + 10) * (yi + 10), (9 - yi) * (9 - yi));
    const int Mz = max((zi + 10) * (zi + 10), (9 - zi) * (9 - zi));
    const int lo = Mx + My + Mz - (HBINS - 1);   // 26th-largest >= lo (27 cells
                                                 // from top-3 per-dim values)
    __shared__ uint32_t h[HBINS];
    __shared__ int lst[LSTMAX];
    __shared__ int sV, cnt;

    if (t < HBINS) h[t] = 0;
    if (t == 0) cnt = 0;
    __syncthreads();

    // generation pass: thread covers (b,c) columns t and t+256
#pragma unroll
    for (int col = 0; col < 2; ++col) {
        int p = t + 256 * col;
        if (p < 400) {
            int bb = p / 20, cc = p - bb * 20;
            int dxv = xi - (bb - 10), dyv = yi - (cc - 10);
            int Dbc = dxv * dxv + dyv * dyv;
#pragma unroll
            for (int a = 0; a < 20; ++a) {
                int dzv = zi - (a - 10);
                int d = Dbc + dzv * dzv;
                if (d >= lo) atomicAdd(&h[d - lo], 1u);
            }
        }
    }
    __syncthreads();

    // single-wave descending scan: V = largest value with suffix-count >= 26
    if (t < 64) {
        int c4[4];
        int cnt4 = 0;
#pragma unroll
        for (int k = 0; k < 4; ++k) {
            int b = (HBINS - 1) - (t * 4 + k);
            c4[k] = (b >= 0) ? (int)h[b] : 0;
            cnt4 += c4[k];
        }
        int incl = cnt4;
        for (int off = 1; off < 64; off <<= 1) {
            int v = __shfl_up(incl, off);
            if (lane >= off) incl += v;
        }
        int P = incl - cnt4;                 // count strictly above my chunk
        if (P < NBRC && incl >= NBRC) {
            int run = P;
#pragma unroll
            for (int k = 0; k < 4; ++k) {
                run += c4[k];
                if (run >= NBRC) { sV = lo + (HBINS - 1) - (t * 4 + k); break; }
            }
        }
    }
    __syncthreads();
    const int V = sV;

    // collect pass: all items with d >= V (count = n1 + ties, << LSTMAX)
#pragma unroll
    for (int col = 0; col < 2; ++col) {
        int p = t + 256 * col;
        if (p < 400) {
            int bb = p / 20, cc = p - bb * 20;
            int dxv = xi - (bb - 10), dyv = yi - (cc - 10);
            int Dbc = dxv * dxv + dyv * dyv;
#pragma unroll
            for (int a = 0; a < 20; ++a) {
                int dzv = zi - (a - 10);
                int d = Dbc + dzv * dzv;
                if (d >= V) {
                    int j = a * 400 + p;
                    int q = atomicAdd(&cnt, 1);
                    if (q < LSTMAX) lst[q] = (d << 13) | (8191 - j);
                }
            }
        }
    }
    __syncthreads();

    // single-wave rank selection: ranks 0..25 are the top-26 in key order
    int n = min(cnt, LSTMAX);
    if (t < 64) {
        for (int base = 0; base < n; base += 64) {
            int idx = base + t;
            int key = (idx < n) ? lst[idx] : -1;
            int rank = 0;
            for (int m = 0; m < n; ++m) rank += (lst[m] > key) ? 1 : 0;
            if (idx < n && rank < NBRC) {
                int j = 8191 - (key & 8191);
                nbrTable[ci * NBRC + rank] = j;
                neededFlag[j] = 1;
            }
        }
    }
}

// ---------------------------------------------------------------------------
// Kernel B: atoms_in_cells = top-5 LARGEST atom distances for NEEDED cells.
// ---------------------------------------------------------------------------
__global__ __launch_bounds__(256) void katoms2(const float* __restrict__ coords,
                                               const int* __restrict__ neededFlag,
                                               int* __restrict__ atomsInCells) {
    const int i = blockIdx.x;
    if (!neededFlag[i]) return;
    __shared__ unsigned long long redB[4];
    const int t = threadIdx.x;
    const int lane = t & 63, wv = t >> 6;

    int xi_, yi_, zi_;
    cell_coords_i(i, xi_, yi_, zi_);
    const float cx = (float)xi_, cy = (float)yi_, cz = (float)zi_;
    const float scell = (float)(xi_ * xi_ + yi_ * yi_ + zi_ * zi_);

    unsigned long long keys[16];
#pragma unroll
    for (int s = 0; s < 16; ++s) {
        int j = t + 256 * s;
        float ax = coords[j * 3], ay = coords[j * 3 + 1], az = coords[j * 3 + 2];
        float sa = __fadd_rn(__fadd_rn(__fmul_rn(ax, ax), __fmul_rn(ay, ay)), __fmul_rn(az, az));
        float dot = __fadd_rn(__fadd_rn(__fmul_rn(cx, ax), __fmul_rn(cy, ay)), __fmul_rn(cz, az));
        float val = __fsub_rn(__fadd_rn(scell, sa), __fmul_rn(2.0f, dot));
        keys[s] = ((unsigned long long)__float_as_uint(val) << 32) | (unsigned int)(4095 - j);
    }

    for (int r = 0; r < KTOP; ++r) {
        unsigned long long best = 0ull;
#pragma unroll
        for (int s = 0; s < 16; ++s) best = umax64(best, keys[s]);
        for (int off = 32; off > 0; off >>= 1)
            best = umax64(best, (unsigned long long)__shfl_xor((long long)best, off));
        if (lane == 0) redB[wv] = best;
        __syncthreads();
        unsigned long long wbest = umax64(umax64(redB[0], redB[1]), umax64(redB[2], redB[3]));
        if (t == 0) atomsInCells[i * KTOP + r] = 4095 - (int)(wbest & 0xFFFFFFFFull);
#pragma unroll
        for (int s = 0; s < 16; ++s) if (keys[s] == wbest) keys[s] = 0ull;
        __syncthreads();
    }
}

// ---------------------------------------------------------------------------
// Kernel D: per-atom gather of 130 candidates, top-8 LARGEST (tie: lower flat
// position), then energy partial -> plain store (no atomics).
// ---------------------------------------------------------------------------
__global__ __launch_bounds__(256) void kenergy(const float* __restrict__ coords,
                                               const float* __restrict__ vdw,
                                               const float* __restrict__ weights,
                                               const int* __restrict__ nbrTable,
                                               const int* __restrict__ atomsInCells,
                                               const int* __restrict__ cellsForAtoms,
                                               float* __restrict__ partials) {
    const int wid = threadIdx.x >> 6;
    const int lane = threadIdx.x & 63;
    const int i = blockIdx.x * 4 + wid;

    const float xi = coords[i * 3], yi = coords[i * 3 + 1], zi = coords[i * 3 + 2];
    const int ci = cellsForAtoms[i];

    int cand[3];
    unsigned long long keys[3];
#pragma unroll
    for (int s = 0; s < 3; ++s) {
        int p = lane + 64 * s;
        cand[s] = -1;
        keys[s] = 0ull;
        if (p < NBRC * KTOP) {
            int cellSlot = p / KTOP;
            int atomSlot = p - cellSlot * KTOP;
            int nc = nbrTable[ci * NBRC + cellSlot];
            int j = atomsInCells[nc * KTOP + atomSlot];
            cand[s] = j;
            float dx = __fsub_rn(xi, coords[j * 3]);
            float dy = __fsub_rn(yi, coords[j * 3 + 1]);
            float dz = __fsub_rn(zi, coords[j * 3 + 2]);
            float dist = __fadd_rn(__fadd_rn(__fmul_rn(dx, dx), __fmul_rn(dy, dy)), __fmul_rn(dz, dz));
            keys[s] = ((unsigned long long)__float_as_uint(dist) << 8) | (unsigned int)(255 - p);
        }
    }

    const float w0 = weights[0], w1 = weights[1], w2 = weights[2];
    const float w3 = weights[3], w4 = weights[4];
    const float vi = vdw[i];

    float esum = 0.0f;
    for (int r = 0; r < MNBR; ++r) {
        unsigned long long best = umax64(umax64(keys[0], keys[1]), keys[2]);
        for (int off = 32; off > 0; off >>= 1)
            best = umax64(best, (unsigned long long)__shfl_xor((long long)best, off));

        int p = 255 - (int)(best & 0xFFull);
        int slot = p >> 6;
        int owner = p & 63;
        int jsel = (slot == 0) ? cand[0] : (slot == 1) ? cand[1] : cand[2];
        int j = __shfl(jsel, owner);
        float dist = __uint_as_float((unsigned int)(best >> 8));

#pragma unroll
        for (int s = 0; s < 3; ++s) if (keys[s] == best) keys[s] = 0ull;

        float rr = __fsqrt_rn(__fadd_rn(dist, 1e-12f));
        float d = __fsub_rn(__fsub_rn(rr, vi), vdw[j]);
        float t1 = __fdiv_rn(d, 0.5f);
        float g1 = expf(-__fmul_rn(t1, t1));
        float t2 = __fdiv_rn(__fsub_rn(d, 3.0f), 2.0f);
        float g2 = expf(-__fmul_rn(t2, t2));
        float rep = (d < 0.0f) ? __fmul_rn(d, d) : 0.0f;
        float hyd = (d < 0.5f) ? 1.0f : ((d < 1.5f) ? __fsub_rn(1.5f, d) : 0.0f);
        float hb = (d < -0.7f) ? 1.0f : ((d < 0.0f) ? __fdiv_rn(-d, 0.7f) : 0.0f);
        float hval = __fadd_rn(__fadd_rn(__fadd_rn(__fadd_rn(
                         __fmul_rn(w0, g1), __fmul_rn(w1, g2)),
                         __fmul_rn(w2, rep)), __fmul_rn(w3, hyd)), __fmul_rn(w4, hb));
        float f = (d < 8.0f) ? hval : 0.0f;
        esum = __fadd_rn(esum, f);
    }
    if (lane == 0) partials[i] = esum;
}

// ---------------------------------------------------------------------------
// Kernel E: deterministic tree reduction + final division.
// ---------------------------------------------------------------------------
__global__ __launch_bounds__(256) void kreduce(const float* __restrict__ partials,
                                               const float* __restrict__ weights,
                                               const float* __restrict__ nrot,
                                               float* __restrict__ out) {
    __shared__ float red[256];
    const int t = threadIdx.x;
    float s = 0.0f;
    for (int k = 0; k < NATOMS / 256; ++k) s = __fadd_rn(s, partials[t + 256 * k]);
    red[t] = s;
    __syncthreads();
    for (int off = 128; off > 0; off >>= 1) {
        if (t < off) red[t] = __fadd_rn(red[t], red[t + off]);
        __syncthreads();
    }
    if (t == 0) out[0] = __fdiv_rn(red[0], __fadd_rn(1.0f, __fmul_rn(weights[5], nrot[0])));
}

extern "C" void kernel_launch(void* const* d_in, const int* in_sizes, int n_in,
                              void* d_out, int out_size, void* d_ws, size_t ws_size,
                              hipStream_t stream) {
    const float* coords  = (const float*)d_in[0];
    const float* vdw     = (const float*)d_in[1];
    const float* weights = (const float*)d_in[2];
    const float* nrot    = (const float*)d_in[3];
    float* out = (float*)d_out;

    int* nbrTable      = (int*)d_ws;                       // 208000
    int* atomsInCells  = nbrTable + NCELLS * NBRC;         // 40000
    int* cellsForAtoms = atomsInCells + NCELLS * KTOP;     // 4096
    int* neededFlag    = cellsForAtoms + NATOMS;           // 8000
    float* partials    = (float*)(neededFlag + NCELLS);    // 4096

    kcellsforatoms<<<NATOMS / 4, 256, 0, stream>>>(coords, cellsForAtoms, neededFlag);
    knbr2<<<NATOMS, 256, 0, stream>>>(cellsForAtoms, nbrTable, neededFlag);
    katoms2<<<NCELLS, 256, 0, stream>>>(coords, neededFlag, atomsInCells);
    kenergy<<<NATOMS / 4, 256, 0, stream>>>(coords, vdw, weights, nbrTable,
                                            atomsInCells, cellsForAtoms, partials);
    kreduce<<<1, 256, 0, stream>>>(partials, weights, nrot, out);
}

// Round 6
// 44.222 us; speedup vs baseline: 2.3573x; 1.0718x over previous
//
#include <hip/hip_runtime.h>
#include <stdint.h>

#define NATOMS 4096
#define NCELLS 8000
#define KTOP 5
#define MNBR 8
#define NBRC 26
#define HBINS 217          // max window: 4*(19*3)-11 = 217 bins
#define LSTMAX 512

__device__ __forceinline__ unsigned long long umax64(unsigned long long a, unsigned long long b) {
    return a > b ? a : b;
}
__device__ __forceinline__ unsigned long long umin64(unsigned long long a, unsigned long long b) {
    return a < b ? a : b;
}

// cells[m] = (g[b], g[c], g[a]) with m = a*400 + b*20 + c, g[t] = t-10
__device__ __forceinline__ void cell_coords_i(int m, int& x, int& y, int& z) {
    int a = m / 400;
    int r = m - a * 400;
    int b = r / 20;
    int c = r - b * 20;
    x = b - 10; y = c - 10; z = a - 10;
}

// ---------------------------------------------------------------------------
// Kernel C: analytic argmin cell (4x4x4 neighborhood of floor(atom); exact
// d^2 gap >= 1.0 dwarfs f32 expansion error ~2e-4). Same f32 formula +
// (bits<<32)|m min-key as the 8000-cell scan -> bitwise identical result.
// Also zeroes neededFlag (consumed only by later kernels -> no race).
// ---------------------------------------------------------------------------
__global__ __launch_bounds__(256) void kcellsforatoms(const float* __restrict__ coords,
                                                      int* __restrict__ cellsForAtoms,
                                                      int* __restrict__ neededFlag) {
    {
        int z = blockIdx.x * 8 + threadIdx.x;
        if (threadIdx.x < 8 && z < NCELLS) neededFlag[z] = 0;
    }
    const int wid = threadIdx.x >> 6;
    const int lane = threadIdx.x & 63;
    const int atom = blockIdx.x * 4 + wid;

    float ax = coords[atom * 3], ay = coords[atom * 3 + 1], az = coords[atom * 3 + 2];
    float sa = __fadd_rn(__fadd_rn(__fmul_rn(ax, ax), __fmul_rn(ay, ay)), __fmul_rn(az, az));

    int fx = (int)floorf(ax), fy = (int)floorf(ay), fz = (int)floorf(az);
    int vx = min(9, max(-10, fx - 1 + (lane & 3)));
    int vy = min(9, max(-10, fy - 1 + ((lane >> 2) & 3)));
    int vz = min(9, max(-10, fz - 1 + (lane >> 4)));
    int m = (vz + 10) * 400 + (vx + 10) * 20 + (vy + 10);

    float cx = (float)vx, cy = (float)vy, cz = (float)vz;
    float scell = (float)(vx * vx + vy * vy + vz * vz);
    float dot = __fadd_rn(__fadd_rn(__fmul_rn(ax, cx), __fmul_rn(ay, cy)), __fmul_rn(az, cz));
    float val = __fsub_rn(__fadd_rn(sa, scell), __fmul_rn(2.0f, dot));
    unsigned long long key = ((unsigned long long)__float_as_uint(val) << 32) | (unsigned int)m;

    for (int off = 32; off > 0; off >>= 1)
        key = umin64(key, (unsigned long long)__shfl_xor((long long)key, off));
    if (lane == 0) cellsForAtoms[atom] = (int)(key & 0xFFFFFFFFull);
}

// ---------------------------------------------------------------------------
// Kernel A: top-26 LARGEST cell-cell sq-dists. One block per ATOM (blocks
// sharing a cell write identical rows - benign).
// Tight per-cell cutoff: with L* = max(c+10, 9-c) per dim, the 27 cells at
// per-dim offsets {L, L-1, L-2} prove 26th-largest >= lo=(Lx-2)^2+(Ly-2)^2+
// (Lz-2)^2. Per (b,c) column, enumerate ONLY the a-ranges with
// dz^2 >= lo-Dbc (analytic integer sqrt) -> ~30-600 candidates/block instead
// of ~4700. Histogram -> cutoff V -> collect d>=V -> single-wave rank-select
// by packed key (d desc, j asc) == jax.lax.top_k tie order.
// ---------------------------------------------------------------------------
__global__ __launch_bounds__(256) void knbr2(const int* __restrict__ cellsForAtoms,
                                             int* __restrict__ nbrTable,
                                             int* __restrict__ neededFlag) {
    const int ci = cellsForAtoms[blockIdx.x];
    const int t = threadIdx.x;
    const int lane = t & 63;

    int xi, yi, zi;
    cell_coords_i(ci, xi, yi, zi);
    const int Lx = max(xi + 10, 9 - xi);
    const int Ly = max(yi + 10, 9 - yi);
    const int Lz = max(zi + 10, 9 - zi);
    const int lo = (Lx - 2) * (Lx - 2) + (Ly - 2) * (Ly - 2) + (Lz - 2) * (Lz - 2);

    __shared__ uint32_t h[HBINS];
    __shared__ int lst[LSTMAX];
    __shared__ int sV, cnt;

    if (t < HBINS) h[t] = 0;
    if (t == 0) cnt = 0;
    __syncthreads();

    // histogram pass: per-column analytic a-ranges
#pragma unroll
    for (int col = 0; col < 2; ++col) {
        int p = t + 256 * col;
        if (p < 400) {
            int bb = p / 20, cc = p - bb * 20;
            int dxv = xi - (bb - 10), dyv = yi - (cc - 10);
            int Dbc = dxv * dxv + dyv * dyv;
            int R = lo - Dbc;
            int aLoEnd = 19, aHiStart = 20;
            if (R > 0) {
                int t0 = (int)ceilf(sqrtf((float)R));
                if ((t0 - 1) * (t0 - 1) >= R) --t0;      // paranoia fixup
                if (t0 * t0 < R) ++t0;
                aLoEnd = min(19, zi + 10 - t0);
                aHiStart = max(0, zi + 10 + t0);
            }
            for (int a = 0; a <= aLoEnd; ++a) {
                int dzv = zi - (a - 10);
                int d = Dbc + dzv * dzv;
                atomicAdd(&h[d - lo], 1u);
            }
            for (int a = aHiStart; a < 20; ++a) {
                int dzv = zi - (a - 10);
                int d = Dbc + dzv * dzv;
                atomicAdd(&h[d - lo], 1u);
            }
        }
    }
    __syncthreads();

    // single-wave descending scan: V = largest value with suffix-count >= 26
    if (t < 64) {
        int c4[4];
        int cnt4 = 0;
#pragma unroll
        for (int k = 0; k < 4; ++k) {
            int b = (HBINS - 1) - (t * 4 + k);
            c4[k] = (b >= 0) ? (int)h[b] : 0;
            cnt4 += c4[k];
        }
        int incl = cnt4;
        for (int off = 1; off < 64; off <<= 1) {
            int v = __shfl_up(incl, off);
            if (lane >= off) incl += v;
        }
        int P = incl - cnt4;                 // count strictly above my chunk
        if (P < NBRC && incl >= NBRC) {
            int run = P;
#pragma unroll
            for (int k = 0; k < 4; ++k) {
                run += c4[k];
                if (run >= NBRC) { sV = lo + (HBINS - 1) - (t * 4 + k); break; }
            }
        }
    }
    __syncthreads();
    const int V = sV;

    // collect pass: all items with d >= V (n1 + ties, << LSTMAX)
#pragma unroll
    for (int col = 0; col < 2; ++col) {
        int p = t + 256 * col;
        if (p < 400) {
            int bb = p / 20, cc = p - bb * 20;
            int dxv = xi - (bb - 10), dyv = yi - (cc - 10);
            int Dbc = dxv * dxv + dyv * dyv;
            int R = V - Dbc;
            int aLoEnd = 19, aHiStart = 20;
            if (R > 0) {
                int t0 = (int)ceilf(sqrtf((float)R));
                if ((t0 - 1) * (t0 - 1) >= R) --t0;
                if (t0 * t0 < R) ++t0;
                aLoEnd = min(19, zi + 10 - t0);
                aHiStart = max(0, zi + 10 + t0);
            }
            for (int a = 0; a <= aLoEnd; ++a) {
                int dzv = zi - (a - 10);
                int d = Dbc + dzv * dzv;
                int j = a * 400 + p;
                int q = atomicAdd(&cnt, 1);
                if (q < LSTMAX) lst[q] = (d << 13) | (8191 - j);
            }
            for (int a = aHiStart; a < 20; ++a) {
                int dzv = zi - (a - 10);
                int d = Dbc + dzv * dzv;
                int j = a * 400 + p;
                int q = atomicAdd(&cnt, 1);
                if (q < LSTMAX) lst[q] = (d << 13) | (8191 - j);
            }
        }
    }
    __syncthreads();

    // single-wave rank selection: ranks 0..25 are the top-26 in key order
    int n = min(cnt, LSTMAX);
    if (t < 64) {
        for (int base = 0; base < n; base += 64) {
            int idx = base + t;
            int key = (idx < n) ? lst[idx] : -1;
            int rank = 0;
            for (int m = 0; m < n; ++m) rank += (lst[m] > key) ? 1 : 0;
            if (idx < n && rank < NBRC) {
                int j = 8191 - (key & 8191);
                nbrTable[ci * NBRC + rank] = j;
                neededFlag[j] = 1;
            }
        }
    }
}

// ---------------------------------------------------------------------------
// Kernel B: atoms_in_cells = top-5 LARGEST atom distances for NEEDED cells.
// ---------------------------------------------------------------------------
__global__ __launch_bounds__(256) void katoms2(const float* __restrict__ coords,
                                               const int* __restrict__ neededFlag,
                                               int* __restrict__ atomsInCells) {
    const int i = blockIdx.x;
    if (!neededFlag[i]) return;
    __shared__ unsigned long long redB[4];
    const int t = threadIdx.x;
    const int lane = t & 63, wv = t >> 6;

    int xi_, yi_, zi_;
    cell_coords_i(i, xi_, yi_, zi_);
    const float cx = (float)xi_, cy = (float)yi_, cz = (float)zi_;
    const float scell = (float)(xi_ * xi_ + yi_ * yi_ + zi_ * zi_);

    unsigned long long keys[16];
#pragma unroll
    for (int s = 0; s < 16; ++s) {
        int j = t + 256 * s;
        float ax = coords[j * 3], ay = coords[j * 3 + 1], az = coords[j * 3 + 2];
        float sa = __fadd_rn(__fadd_rn(__fmul_rn(ax, ax), __fmul_rn(ay, ay)), __fmul_rn(az, az));
        float dot = __fadd_rn(__fadd_rn(__fmul_rn(cx, ax), __fmul_rn(cy, ay)), __fmul_rn(cz, az));
        float val = __fsub_rn(__fadd_rn(scell, sa), __fmul_rn(2.0f, dot));
        keys[s] = ((unsigned long long)__float_as_uint(val) << 32) | (unsigned int)(4095 - j);
    }

    for (int r = 0; r < KTOP; ++r) {
        unsigned long long best = 0ull;
#pragma unroll
        for (int s = 0; s < 16; ++s) best = umax64(best, keys[s]);
        for (int off = 32; off > 0; off >>= 1)
            best = umax64(best, (unsigned long long)__shfl_xor((long long)best, off));
        if (lane == 0) redB[wv] = best;
        __syncthreads();
        unsigned long long wbest = umax64(umax64(redB[0], redB[1]), umax64(redB[2], redB[3]));
        if (t == 0) atomsInCells[i * KTOP + r] = 4095 - (int)(wbest & 0xFFFFFFFFull);
#pragma unroll
        for (int s = 0; s < 16; ++s) if (keys[s] == wbest) keys[s] = 0ull;
        __syncthreads();
    }
}

// ---------------------------------------------------------------------------
// Kernel D: per-atom gather of 130 candidates, top-8 LARGEST (tie: lower flat
// position), then energy partial -> plain store (no atomics).
// ---------------------------------------------------------------------------
__global__ __launch_bounds__(256) void kenergy(const float* __restrict__ coords,
                                               const float* __restrict__ vdw,
                                               const float* __restrict__ weights,
                                               const int* __restrict__ nbrTable,
                                               const int* __restrict__ atomsInCells,
                                               const int* __restrict__ cellsForAtoms,
                                               float* __restrict__ partials) {
    const int wid = threadIdx.x >> 6;
    const int lane = threadIdx.x & 63;
    const int i = blockIdx.x * 4 + wid;

    const float xi = coords[i * 3], yi = coords[i * 3 + 1], zi = coords[i * 3 + 2];
    const int ci = cellsForAtoms[i];

    int cand[3];
    unsigned long long keys[3];
#pragma unroll
    for (int s = 0; s < 3; ++s) {
        int p = lane + 64 * s;
        cand[s] = -1;
        keys[s] = 0ull;
        if (p < NBRC * KTOP) {
            int cellSlot = p / KTOP;
            int atomSlot = p - cellSlot * KTOP;
            int nc = nbrTable[ci * NBRC + cellSlot];
            int j = atomsInCells[nc * KTOP + atomSlot];
            cand[s] = j;
            float dx = __fsub_rn(xi, coords[j * 3]);
            float dy = __fsub_rn(yi, coords[j * 3 + 1]);
            float dz = __fsub_rn(zi, coords[j * 3 + 2]);
            float dist = __fadd_rn(__fadd_rn(__fmul_rn(dx, dx), __fmul_rn(dy, dy)), __fmul_rn(dz, dz));
            keys[s] = ((unsigned long long)__float_as_uint(dist) << 8) | (unsigned int)(255 - p);
        }
    }

    const float w0 = weights[0], w1 = weights[1], w2 = weights[2];
    const float w3 = weights[3], w4 = weights[4];
    const float vi = vdw[i];

    float esum = 0.0f;
    for (int r = 0; r < MNBR; ++r) {
        unsigned long long best = umax64(umax64(keys[0], keys[1]), keys[2]);
        for (int off = 32; off > 0; off >>= 1)
            best = umax64(best, (unsigned long long)__shfl_xor((long long)best, off));

        int p = 255 - (int)(best & 0xFFull);
        int slot = p >> 6;
        int owner = p & 63;
        int jsel = (slot == 0) ? cand[0] : (slot == 1) ? cand[1] : cand[2];
        int j = __shfl(jsel, owner);
        float dist = __uint_as_float((unsigned int)(best >> 8));

#pragma unroll
        for (int s = 0; s < 3; ++s) if (keys[s] == best) keys[s] = 0ull;

        float rr = __fsqrt_rn(__fadd_rn(dist, 1e-12f));
        float d = __fsub_rn(__fsub_rn(rr, vi), vdw[j]);
        float t1 = __fdiv_rn(d, 0.5f);
        float g1 = expf(-__fmul_rn(t1, t1));
        float t2 = __fdiv_rn(__fsub_rn(d, 3.0f), 2.0f);
        float g2 = expf(-__fmul_rn(t2, t2));
        float rep = (d < 0.0f) ? __fmul_rn(d, d) : 0.0f;
        float hyd = (d < 0.5f) ? 1.0f : ((d < 1.5f) ? __fsub_rn(1.5f, d) : 0.0f);
        float hb = (d < -0.7f) ? 1.0f : ((d < 0.0f) ? __fdiv_rn(-d, 0.7f) : 0.0f);
        float hval = __fadd_rn(__fadd_rn(__fadd_rn(__fadd_rn(
                         __fmul_rn(w0, g1), __fmul_rn(w1, g2)),
                         __fmul_rn(w2, rep)), __fmul_rn(w3, hyd)), __fmul_rn(w4, hb));
        float f = (d < 8.0f) ? hval : 0.0f;
        esum = __fadd_rn(esum, f);
    }
    if (lane == 0) partials[i] = esum;
}

// ---------------------------------------------------------------------------
// Kernel E: deterministic tree reduction + final division.
// ---------------------------------------------------------------------------
__global__ __launch_bounds__(256) void kreduce(const float* __restrict__ partials,
                                               const float* __restrict__ weights,
                                               const float* __restrict__ nrot,
                                               float* __restrict__ out) {
    __shared__ float red[256];
    const int t = threadIdx.x;
    float s = 0.0f;
    for (int k = 0; k < NATOMS / 256; ++k) s = __fadd_rn(s, partials[t + 256 * k]);
    red[t] = s;
    __syncthreads();
    for (int off = 128; off > 0; off >>= 1) {
        if (t < off) red[t] = __fadd_rn(red[t], red[t + off]);
        __syncthreads();
    }
    if (t == 0) out[0] = __fdiv_rn(red[0], __fadd_rn(1.0f, __fmul_rn(weights[5], nrot[0])));
}

extern "C" void kernel_launch(void* const* d_in, const int* in_sizes, int n_in,
                              void* d_out, int out_size, void* d_ws, size_t ws_size,
                              hipStream_t stream) {
    const float* coords  = (const float*)d_in[0];
    const float* vdw     = (const float*)d_in[1];
    const float* weights = (const float*)d_in[2];
    const float* nrot    = (const float*)d_in[3];
    float* out = (float*)d_out;

    int* nbrTable      = (int*)d_ws;                       // 208000
    int* atomsInCells  = nbrTable + NCELLS * NBRC;         // 40000
    int* cellsForAtoms = atomsInCells + NCELLS * KTOP;     // 4096
    int* neededFlag    = cellsForAtoms + NATOMS;           // 8000
    float* partials    = (float*)(neededFlag + NCELLS);    // 4096

    kcellsforatoms<<<NATOMS / 4, 256, 0, stream>>>(coords, cellsForAtoms, neededFlag);
    knbr2<<<NATOMS, 256, 0, stream>>>(cellsForAtoms, nbrTable, neededFlag);
    katoms2<<<NCELLS, 256, 0, stream>>>(coords, neededFlag, atomsInCells);
    kenergy<<<NATOMS / 4, 256, 0, stream>>>(coords, vdw, weights, nbrTable,
                                            atomsInCells, cellsForAtoms, partials);
    kreduce<<<1, 256, 0, stream>>>(partials, weights, nrot, out);
}